// Round 1
// baseline (2793.338 us; speedup 1.0000x reference)
//
#include <hip/hip_runtime.h>
#include <hip/hip_bf16.h>
#include <float.h>

#define LRELU(x) ((x) > 0.0f ? (x) : 0.01f * (x))

// ---------------------------------------------------------------------------
// K1: deg = 1 (self loop), xw = X @ W1^T   (X: [N,4], W1: [16,4])
// ---------------------------------------------------------------------------
__global__ __launch_bounds__(256) void k_init(const float* __restrict__ X,
                                              const float* __restrict__ W1,
                                              float* __restrict__ deg,
                                              float* __restrict__ xw, int N) {
    int i = blockIdx.x * blockDim.x + threadIdx.x;
    if (i >= N) return;
    deg[i] = 1.0f;
    const float4 x = *reinterpret_cast<const float4*>(X + 4 * i);
    float o[16];
#pragma unroll
    for (int g = 0; g < 16; ++g) {
        const float4 wr = *reinterpret_cast<const float4*>(W1 + 4 * g);
        o[g] = x.x * wr.x + x.y * wr.y + x.z * wr.z + x.w * wr.w;
    }
    float4* dst = reinterpret_cast<float4*>(xw + 16 * i);
#pragma unroll
    for (int k = 0; k < 4; ++k)
        dst[k] = make_float4(o[4 * k], o[4 * k + 1], o[4 * k + 2], o[4 * k + 3]);
}

// ---------------------------------------------------------------------------
// K2: deg[col] += w  for edges with col > row
// ---------------------------------------------------------------------------
__global__ __launch_bounds__(256) void k_deg(const int* __restrict__ row,
                                             const int* __restrict__ col,
                                             const float* __restrict__ w,
                                             float* __restrict__ deg, int E) {
    int e = blockIdx.x * blockDim.x + threadIdx.x;
    if (e >= E) return;
    int r = row[e], c = col[e];
    if (c > r) atomicAdd(deg + c, w[e]);
}

// ---------------------------------------------------------------------------
// K3: dinv = rsqrt(deg) (in place); acc = dinv^2 * xw  (self-loop term)
// ---------------------------------------------------------------------------
__global__ __launch_bounds__(256) void k_self(float* __restrict__ deg_dinv,
                                              const float* __restrict__ xw,
                                              float* __restrict__ acc, int N) {
    int i = blockIdx.x * blockDim.x + threadIdx.x;
    if (i >= N) return;
    float d = rsqrtf(deg_dinv[i]);
    deg_dinv[i] = d;
    float s = d * d;
    const float4* xs = reinterpret_cast<const float4*>(xw + 16 * i);
    float4* as = reinterpret_cast<float4*>(acc + 16 * i);
#pragma unroll
    for (int k = 0; k < 4; ++k) {
        float4 v = xs[k];
        as[k] = make_float4(s * v.x, s * v.y, s * v.z, s * v.w);
    }
}

// ---------------------------------------------------------------------------
// K4/K6: edge scatter  acc[col][g] += dinv[row]*w*dinv[col] * xw[row][g]
// ---------------------------------------------------------------------------
__global__ __launch_bounds__(256) void k_scatter(const int* __restrict__ row,
                                                 const int* __restrict__ col,
                                                 const float* __restrict__ w,
                                                 const float* __restrict__ dinv,
                                                 const float* __restrict__ xw,
                                                 float* __restrict__ acc, int E) {
    int e = blockIdx.x * blockDim.x + threadIdx.x;
    if (e >= E) return;
    int r = row[e], c = col[e];
    if (c <= r) return;
    float nrm = dinv[r] * w[e] * dinv[c];
    const float4* xr = reinterpret_cast<const float4*>(xw + 16 * r);
    float* ac = acc + 16 * c;
#pragma unroll
    for (int k = 0; k < 4; ++k) {
        float4 v = xr[k];
        atomicAdd(ac + 4 * k + 0, nrm * v.x);
        atomicAdd(ac + 4 * k + 1, nrm * v.y);
        atomicAdd(ac + 4 * k + 2, nrm * v.z);
        atomicAdd(ac + 4 * k + 3, nrm * v.w);
    }
}

// ---------------------------------------------------------------------------
// K5: h1 = lrelu(acc + b1); xw = h1 @ W2^T; acc = dinv^2 * xw
// ---------------------------------------------------------------------------
__global__ __launch_bounds__(256) void k_mid(const float* __restrict__ b1,
                                             const float* __restrict__ W2,
                                             const float* __restrict__ dinv,
                                             float* __restrict__ xw,
                                             float* __restrict__ acc, int N) {
    int i = blockIdx.x * blockDim.x + threadIdx.x;
    if (i >= N) return;
    float h[16];
#pragma unroll
    for (int g = 0; g < 16; ++g) {
        float v = acc[16 * i + g] + b1[g];
        h[g] = LRELU(v);
    }
    float d = dinv[i];
    float s = d * d;
#pragma unroll
    for (int g = 0; g < 16; ++g) {
        float a = 0.0f;
#pragma unroll
        for (int k = 0; k < 16; ++k) a += h[k] * W2[16 * g + k];
        xw[16 * i + g] = a;
        acc[16 * i + g] = s * a;
    }
}

// ---------------------------------------------------------------------------
// K7: per-graph mean/max pool over lrelu(acc + b2), then both MLP heads.
// One wave (64 threads) per graph. Batching is sorted -> contiguous ranges.
// ---------------------------------------------------------------------------
__global__ __launch_bounds__(64) void k_pool(const float* __restrict__ acc,
                                             const float* __restrict__ b2,
                                             const int* __restrict__ batching,
                                             int N,
                                             const float* __restrict__ C1w, const float* __restrict__ C1b,
                                             const float* __restrict__ C2w, const float* __restrict__ C2b,
                                             const float* __restrict__ C3w, const float* __restrict__ C3b,
                                             const float* __restrict__ R1w, const float* __restrict__ R1b,
                                             const float* __restrict__ R2w, const float* __restrict__ R2b,
                                             const float* __restrict__ R3w, const float* __restrict__ R3b,
                                             float* __restrict__ out) {
    int b = blockIdx.x;
    int t = threadIdx.x;
    __shared__ int s_se[2];
    __shared__ float sp[32];
    __shared__ float h1s[64];
    __shared__ float h2s[64];
    if (t < 2) {
        int target = b + t;
        int lo = 0, hi = N;
        while (lo < hi) {
            int mid = (lo + hi) >> 1;
            if (batching[mid] < target) lo = mid + 1; else hi = mid;
        }
        s_se[t] = lo;
    }
    __syncthreads();
    int start = s_se[0], end = s_se[1];
    int g = t & 15, sub = t >> 4;                 // 16 dims x 4 node-lanes
    float bg = b2[g];
    float sum = 0.0f, mx = -FLT_MAX;
    for (int n = start + sub; n < end; n += 4) {
        float v = acc[16 * n + g] + bg;
        v = LRELU(v);
        sum += v;
        mx = fmaxf(mx, v);
    }
    // reduce the 4 node-lanes (tid strides of 16)
    sum += __shfl_down(sum, 32);
    mx = fmaxf(mx, __shfl_down(mx, 32));
    sum += __shfl_down(sum, 16);
    mx = fmaxf(mx, __shfl_down(mx, 16));
    if (t < 16) {
        float cnt = (float)(end - start);
        sp[t] = sum / fmaxf(cnt, 1.0f);
        sp[16 + t] = mx;
    }
    __syncthreads();
    // layer 1 of both heads: threads 0..31 -> C head, 32..63 -> R head
    int d = t & 31;
    const float* W1h = (t < 32) ? C1w : R1w;
    const float* b1h = (t < 32) ? C1b : R1b;
    float a1 = b1h[d];
#pragma unroll 4
    for (int k = 0; k < 32; ++k) a1 += sp[k] * W1h[32 * d + k];
    h1s[t] = LRELU(a1);
    __syncthreads();
    const float* W2h = (t < 32) ? C2w : R2w;
    const float* b2h = (t < 32) ? C2b : R2b;
    const float* h1base = h1s + (t < 32 ? 0 : 32);
    float a2 = b2h[d];
#pragma unroll 4
    for (int k = 0; k < 32; ++k) a2 += h1base[k] * W2h[32 * d + k];
    h2s[t] = LRELU(a2);
    __syncthreads();
    if (t == 0 || t == 32) {
        const float* w3 = (t == 0) ? C3w : R3w;
        float a3 = (t == 0) ? C3b[0] : R3b[0];
        const float* hb = h2s + t;
#pragma unroll 4
        for (int k = 0; k < 32; ++k) a3 += hb[k] * w3[k];
        out[2 * b + (t >> 5)] = a3;
    }
}

// ---------------------------------------------------------------------------
extern "C" void kernel_launch(void* const* d_in, const int* in_sizes, int n_in,
                              void* d_out, int out_size, void* d_ws, size_t ws_size,
                              hipStream_t stream) {
    const float* X   = (const float*)d_in[0];
    const int*   EI  = (const int*)d_in[1];
    const float* EW  = (const float*)d_in[2];
    const int*   Bat = (const int*)d_in[3];
    // d_in[4] = num_graphs (device scalar; grid size derived from out_size)
    const float* W1  = (const float*)d_in[5];
    const float* b1  = (const float*)d_in[6];
    const float* W2  = (const float*)d_in[7];
    const float* b2  = (const float*)d_in[8];
    const float* C1w = (const float*)d_in[9];
    const float* C1b = (const float*)d_in[10];
    const float* C2w = (const float*)d_in[11];
    const float* C2b = (const float*)d_in[12];
    const float* C3w = (const float*)d_in[13];
    const float* C3b = (const float*)d_in[14];
    const float* R1w = (const float*)d_in[15];
    const float* R1b = (const float*)d_in[16];
    const float* R2w = (const float*)d_in[17];
    const float* R2b = (const float*)d_in[18];
    const float* R3w = (const float*)d_in[19];
    const float* R3b = (const float*)d_in[20];

    const int N = in_sizes[0] / 4;
    const int E = in_sizes[1] / 2;
    const int B = out_size / 2;
    const int* row = EI;
    const int* col = EI + E;

    float* deg = (float*)d_ws;        // N floats (becomes dinv in place)
    float* xw  = deg + N;             // 16N floats
    float* acc = xw + 16 * (size_t)N; // 16N floats
    float* outp = (float*)d_out;

    dim3 blk(256);
    dim3 gN((N + 255) / 256);
    dim3 gE((E + 255) / 256);

    k_init<<<gN, blk, 0, stream>>>(X, W1, deg, xw, N);
    k_deg<<<gE, blk, 0, stream>>>(row, col, EW, deg, E);
    k_self<<<gN, blk, 0, stream>>>(deg, xw, acc, N);
    k_scatter<<<gE, blk, 0, stream>>>(row, col, EW, deg, xw, acc, E);
    k_mid<<<gN, blk, 0, stream>>>(b1, W2, deg, xw, acc, N);
    k_scatter<<<gE, blk, 0, stream>>>(row, col, EW, deg, xw, acc, E);
    k_pool<<<dim3(B), dim3(64), 0, stream>>>(acc, b2, Bat, N,
                                             C1w, C1b, C2w, C2b, C3w, C3b,
                                             R1w, R1b, R2w, R2b, R3w, R3b,
                                             outp);
}

// Round 2
// 374.025 us; speedup vs baseline: 7.4683x; 7.4683x over previous
//
#include <hip/hip_runtime.h>
#include <hip/hip_bf16.h>
#include <float.h>

#define LRELU(x) ((x) > 0.0f ? (x) : 0.01f * (x))

// ---------------------------------------------------------------------------
// K1: deg = 1 (self loop), cnt = 0, xw = X @ W1^T   (X: [N,4], W1: [16,4])
// ---------------------------------------------------------------------------
__global__ __launch_bounds__(256) void k_init(const float* __restrict__ X,
                                              const float* __restrict__ W1,
                                              float* __restrict__ deg,
                                              int* __restrict__ cnt,
                                              float* __restrict__ xw, int N) {
    int i = blockIdx.x * blockDim.x + threadIdx.x;
    if (i >= N) return;
    deg[i] = 1.0f;
    cnt[i] = 0;
    const float4 x = *reinterpret_cast<const float4*>(X + 4 * i);
    float o[16];
#pragma unroll
    for (int g = 0; g < 16; ++g) {
        const float4 wr = *reinterpret_cast<const float4*>(W1 + 4 * g);
        o[g] = x.x * wr.x + x.y * wr.y + x.z * wr.z + x.w * wr.w;
    }
    float4* dst = reinterpret_cast<float4*>(xw + 16 * i);
#pragma unroll
    for (int k = 0; k < 4; ++k)
        dst[k] = make_float4(o[4 * k], o[4 * k + 1], o[4 * k + 2], o[4 * k + 3]);
}

// ---------------------------------------------------------------------------
// K2: deg[col] += w and cnt[col]++  for edges with col > row
// ---------------------------------------------------------------------------
__global__ __launch_bounds__(256) void k_count(const int* __restrict__ row,
                                               const int* __restrict__ col,
                                               const float* __restrict__ w,
                                               float* __restrict__ deg,
                                               int* __restrict__ cnt, int E) {
    int e = blockIdx.x * blockDim.x + threadIdx.x;
    if (e >= E) return;
    int r = row[e], c = col[e];
    if (c > r) {
        atomicAdd(deg + c, w[e]);
        atomicAdd(cnt + c, 1);
    }
}

// ---------------------------------------------------------------------------
// Scan stage 1: per-block (1024 elems) exclusive scan of cnt -> offs (block-
// relative), block totals -> partials[blk]
// ---------------------------------------------------------------------------
__global__ __launch_bounds__(256) void k_scan1(const int* __restrict__ cnt,
                                               int* __restrict__ offs,
                                               int* __restrict__ partials, int N) {
    __shared__ int sm[256];
    int tid = threadIdx.x;
    int base = blockIdx.x * 1024 + tid * 4;
    int v[4];
    int s = 0;
#pragma unroll
    for (int k = 0; k < 4; ++k) {
        int idx = base + k;
        v[k] = (idx < N) ? cnt[idx] : 0;
        s += v[k];
    }
    sm[tid] = s;
    __syncthreads();
    for (int off = 1; off < 256; off <<= 1) {
        int t = (tid >= off) ? sm[tid - off] : 0;
        __syncthreads();
        sm[tid] += t;
        __syncthreads();
    }
    int run = sm[tid] - s;   // exclusive prefix of this thread's 4-chunk
#pragma unroll
    for (int k = 0; k < 4; ++k) {
        int idx = base + k;
        if (idx < N) offs[idx] = run;
        run += v[k];
    }
    if (tid == 255) partials[blockIdx.x] = sm[255];
}

// ---------------------------------------------------------------------------
// Scan stage 2: exclusive scan of <=256 block totals; writes offs[N] = total
// ---------------------------------------------------------------------------
__global__ __launch_bounds__(256) void k_scan2(int* __restrict__ partials,
                                               int* __restrict__ offs, int nb, int N) {
    __shared__ int sm[256];
    int tid = threadIdx.x;
    int v = (tid < nb) ? partials[tid] : 0;
    sm[tid] = v;
    __syncthreads();
    for (int off = 1; off < 256; off <<= 1) {
        int t = (tid >= off) ? sm[tid - off] : 0;
        __syncthreads();
        sm[tid] += t;
        __syncthreads();
    }
    if (tid < nb) partials[tid] = sm[tid] - v;  // exclusive
    if (tid == nb - 1) offs[N] = sm[tid];       // grand total
}

// ---------------------------------------------------------------------------
// Scan stage 3 + self-loop: offs += partials[blk]; cursor = offs;
// dinv = rsqrt(deg) in place; acc = dinv^2 * xw
// ---------------------------------------------------------------------------
__global__ __launch_bounds__(256) void k_self3(int* __restrict__ offs,
                                               int* __restrict__ cursor,
                                               const int* __restrict__ partials,
                                               float* __restrict__ deg_dinv,
                                               const float* __restrict__ xw,
                                               float* __restrict__ acc, int N) {
    int i = blockIdx.x * blockDim.x + threadIdx.x;
    if (i >= N) return;
    int o = offs[i] + partials[i >> 10];
    offs[i] = o;
    cursor[i] = o;
    float d = rsqrtf(deg_dinv[i]);
    deg_dinv[i] = d;
    float s = d * d;
    const float4* xs = reinterpret_cast<const float4*>(xw + 16 * i);
    float4* as = reinterpret_cast<float4*>(acc + 16 * i);
#pragma unroll
    for (int k = 0; k < 4; ++k) {
        float4 v = xs[k];
        as[k] = make_float4(s * v.x, s * v.y, s * v.z, s * v.w);
    }
}

// ---------------------------------------------------------------------------
// Fill CSR: pack[pos] = (row, nrm) bucketed by col
// ---------------------------------------------------------------------------
__global__ __launch_bounds__(256) void k_fill(const int* __restrict__ row,
                                              const int* __restrict__ col,
                                              const float* __restrict__ w,
                                              const float* __restrict__ dinv,
                                              int* __restrict__ cursor,
                                              int2* __restrict__ pack, int E) {
    int e = blockIdx.x * blockDim.x + threadIdx.x;
    if (e >= E) return;
    int r = row[e], c = col[e];
    if (c <= r) return;
    float nrm = dinv[r] * w[e] * dinv[c];
    int pos = atomicAdd(cursor + c, 1);
    pack[pos] = make_int2(r, __float_as_int(nrm));
}

// ---------------------------------------------------------------------------
// Gather: thread (c,g): acc[c][g] += sum_j nrm_j * xw[r_j][g]   (no atomics)
// ---------------------------------------------------------------------------
__global__ __launch_bounds__(256) void k_gather(const int* __restrict__ offs,
                                                const int2* __restrict__ pack,
                                                const float* __restrict__ xw,
                                                float* __restrict__ acc, int N) {
    int t = blockIdx.x * blockDim.x + threadIdx.x;
    if (t >= 16 * N) return;
    int c = t >> 4, g = t & 15;
    int beg = offs[c], end = offs[c + 1];
    float a = acc[t];
    for (int j = beg; j < end; ++j) {
        int2 p = pack[j];
        a += __int_as_float(p.y) * xw[((size_t)p.x << 4) + g];
    }
    acc[t] = a;
}

// ---------------------------------------------------------------------------
// K5: h1 = lrelu(acc + b1); xw = h1 @ W2^T; acc = dinv^2 * xw
// ---------------------------------------------------------------------------
__global__ __launch_bounds__(256) void k_mid(const float* __restrict__ b1,
                                             const float* __restrict__ W2,
                                             const float* __restrict__ dinv,
                                             float* __restrict__ xw,
                                             float* __restrict__ acc, int N) {
    int i = blockIdx.x * blockDim.x + threadIdx.x;
    if (i >= N) return;
    float h[16];
#pragma unroll
    for (int g = 0; g < 16; ++g) {
        float v = acc[16 * i + g] + b1[g];
        h[g] = LRELU(v);
    }
    float d = dinv[i];
    float s = d * d;
#pragma unroll
    for (int g = 0; g < 16; ++g) {
        float a = 0.0f;
#pragma unroll
        for (int k = 0; k < 16; ++k) a += h[k] * W2[16 * g + k];
        xw[16 * i + g] = a;
        acc[16 * i + g] = s * a;
    }
}

// ---------------------------------------------------------------------------
// Fallback kernels (atomic scatter path, used only if ws too small)
// ---------------------------------------------------------------------------
__global__ __launch_bounds__(256) void k_self(float* __restrict__ deg_dinv,
                                              const float* __restrict__ xw,
                                              float* __restrict__ acc, int N) {
    int i = blockIdx.x * blockDim.x + threadIdx.x;
    if (i >= N) return;
    float d = rsqrtf(deg_dinv[i]);
    deg_dinv[i] = d;
    float s = d * d;
    const float4* xs = reinterpret_cast<const float4*>(xw + 16 * i);
    float4* as = reinterpret_cast<float4*>(acc + 16 * i);
#pragma unroll
    for (int k = 0; k < 4; ++k) {
        float4 v = xs[k];
        as[k] = make_float4(s * v.x, s * v.y, s * v.z, s * v.w);
    }
}

__global__ __launch_bounds__(256) void k_scatter(const int* __restrict__ row,
                                                 const int* __restrict__ col,
                                                 const float* __restrict__ w,
                                                 const float* __restrict__ dinv,
                                                 const float* __restrict__ xw,
                                                 float* __restrict__ acc, int E) {
    int e = blockIdx.x * blockDim.x + threadIdx.x;
    if (e >= E) return;
    int r = row[e], c = col[e];
    if (c <= r) return;
    float nrm = dinv[r] * w[e] * dinv[c];
    const float4* xr = reinterpret_cast<const float4*>(xw + 16 * r);
    float* ac = acc + 16 * c;
#pragma unroll
    for (int k = 0; k < 4; ++k) {
        float4 v = xr[k];
        atomicAdd(ac + 4 * k + 0, nrm * v.x);
        atomicAdd(ac + 4 * k + 1, nrm * v.y);
        atomicAdd(ac + 4 * k + 2, nrm * v.z);
        atomicAdd(ac + 4 * k + 3, nrm * v.w);
    }
}

// ---------------------------------------------------------------------------
// K7: per-graph mean/max pool over lrelu(acc + b2), then both MLP heads.
// ---------------------------------------------------------------------------
__global__ __launch_bounds__(64) void k_pool(const float* __restrict__ acc,
                                             const float* __restrict__ b2,
                                             const int* __restrict__ batching,
                                             int N,
                                             const float* __restrict__ C1w, const float* __restrict__ C1b,
                                             const float* __restrict__ C2w, const float* __restrict__ C2b,
                                             const float* __restrict__ C3w, const float* __restrict__ C3b,
                                             const float* __restrict__ R1w, const float* __restrict__ R1b,
                                             const float* __restrict__ R2w, const float* __restrict__ R2b,
                                             const float* __restrict__ R3w, const float* __restrict__ R3b,
                                             float* __restrict__ out) {
    int b = blockIdx.x;
    int t = threadIdx.x;
    __shared__ int s_se[2];
    __shared__ float sp[32];
    __shared__ float h1s[64];
    __shared__ float h2s[64];
    if (t < 2) {
        int target = b + t;
        int lo = 0, hi = N;
        while (lo < hi) {
            int mid = (lo + hi) >> 1;
            if (batching[mid] < target) lo = mid + 1; else hi = mid;
        }
        s_se[t] = lo;
    }
    __syncthreads();
    int start = s_se[0], end = s_se[1];
    int g = t & 15, sub = t >> 4;
    float bg = b2[g];
    float sum = 0.0f, mx = -FLT_MAX;
    for (int n = start + sub; n < end; n += 4) {
        float v = acc[16 * n + g] + bg;
        v = LRELU(v);
        sum += v;
        mx = fmaxf(mx, v);
    }
    sum += __shfl_down(sum, 32);
    mx = fmaxf(mx, __shfl_down(mx, 32));
    sum += __shfl_down(sum, 16);
    mx = fmaxf(mx, __shfl_down(mx, 16));
    if (t < 16) {
        float cnt = (float)(end - start);
        sp[t] = sum / fmaxf(cnt, 1.0f);
        sp[16 + t] = mx;
    }
    __syncthreads();
    int d = t & 31;
    const float* W1h = (t < 32) ? C1w : R1w;
    const float* b1h = (t < 32) ? C1b : R1b;
    float a1 = b1h[d];
#pragma unroll 4
    for (int k = 0; k < 32; ++k) a1 += sp[k] * W1h[32 * d + k];
    h1s[t] = LRELU(a1);
    __syncthreads();
    const float* W2h = (t < 32) ? C2w : R2w;
    const float* b2h = (t < 32) ? C2b : R2b;
    const float* h1base = h1s + (t < 32 ? 0 : 32);
    float a2 = b2h[d];
#pragma unroll 4
    for (int k = 0; k < 32; ++k) a2 += h1base[k] * W2h[32 * d + k];
    h2s[t] = LRELU(a2);
    __syncthreads();
    if (t == 0 || t == 32) {
        const float* w3 = (t == 0) ? C3w : R3w;
        float a3 = (t == 0) ? C3b[0] : R3b[0];
        const float* hb = h2s + t;
#pragma unroll 4
        for (int k = 0; k < 32; ++k) a3 += hb[k] * w3[k];
        out[2 * b + (t >> 5)] = a3;
    }
}

// ---------------------------------------------------------------------------
extern "C" void kernel_launch(void* const* d_in, const int* in_sizes, int n_in,
                              void* d_out, int out_size, void* d_ws, size_t ws_size,
                              hipStream_t stream) {
    const float* X   = (const float*)d_in[0];
    const int*   EI  = (const int*)d_in[1];
    const float* EW  = (const float*)d_in[2];
    const int*   Bat = (const int*)d_in[3];
    const float* W1  = (const float*)d_in[5];
    const float* b1  = (const float*)d_in[6];
    const float* W2  = (const float*)d_in[7];
    const float* b2  = (const float*)d_in[8];
    const float* C1w = (const float*)d_in[9];
    const float* C1b = (const float*)d_in[10];
    const float* C2w = (const float*)d_in[11];
    const float* C2b = (const float*)d_in[12];
    const float* C3w = (const float*)d_in[13];
    const float* C3b = (const float*)d_in[14];
    const float* R1w = (const float*)d_in[15];
    const float* R1b = (const float*)d_in[16];
    const float* R2w = (const float*)d_in[17];
    const float* R2b = (const float*)d_in[18];
    const float* R3w = (const float*)d_in[19];
    const float* R3b = (const float*)d_in[20];

    const int N = in_sizes[0] / 4;
    const int E = in_sizes[1] / 2;
    const int B = out_size / 2;
    const int* row = EI;
    const int* col = EI + E;

    float* outp = (float*)d_out;

    // workspace layout
    size_t off = 0;
    float* deg  = (float*)d_ws;            off += (size_t)N;          // N (becomes dinv)
    float* xw   = (float*)d_ws + off;      off += 16 * (size_t)N;     // 16N
    float* acc  = (float*)d_ws + off;      off += 16 * (size_t)N;     // 16N
    int*   cnt  = (int*)d_ws + off;        off += (size_t)N;          // N (histogram -> reused)
    int*   offs = (int*)d_ws + off;        off += (size_t)N + 1;      // N+1
    int*   curs = (int*)d_ws + off;        off += (size_t)N;          // N
    int*   part = (int*)d_ws + off;        off += 256;                // block partials
    off = (off + 1) & ~(size_t)1;                                     // 8B align
    int2*  pack = (int2*)((int*)d_ws + off);                          // E entries (8B each)
    size_t needed = off * 4 + (size_t)E * 8;

    const int nb = (N + 1023) / 1024;      // scan blocks

    dim3 blk(256);
    dim3 gN((N + 255) / 256);
    dim3 gE((E + 255) / 256);
    dim3 gNG((16 * N + 255) / 256);

    if (needed <= ws_size && nb <= 256) {
        // CSR gather path (no float atomics in the hot loop)
        k_init <<<gN, blk, 0, stream>>>(X, W1, deg, cnt, xw, N);
        k_count<<<gE, blk, 0, stream>>>(row, col, EW, deg, cnt, E);
        k_scan1<<<dim3(nb), blk, 0, stream>>>(cnt, offs, part, N);
        k_scan2<<<dim3(1), blk, 0, stream>>>(part, offs, nb, N);
        k_self3<<<gN, blk, 0, stream>>>(offs, curs, part, deg, xw, acc, N);
        k_fill <<<gE, blk, 0, stream>>>(row, col, EW, deg, curs, pack, E);
        k_gather<<<gNG, blk, 0, stream>>>(offs, pack, xw, acc, N);
        k_mid  <<<gN, blk, 0, stream>>>(b1, W2, deg, xw, acc, N);
        k_gather<<<gNG, blk, 0, stream>>>(offs, pack, xw, acc, N);
    } else {
        // fallback: atomic scatter path
        k_init <<<gN, blk, 0, stream>>>(X, W1, deg, cnt, xw, N);
        k_count<<<gE, blk, 0, stream>>>(row, col, EW, deg, cnt, E);
        k_self <<<gN, blk, 0, stream>>>(deg, xw, acc, N);
        k_scatter<<<gE, blk, 0, stream>>>(row, col, EW, deg, xw, acc, E);
        k_mid  <<<gN, blk, 0, stream>>>(b1, W2, deg, xw, acc, N);
        k_scatter<<<gE, blk, 0, stream>>>(row, col, EW, deg, xw, acc, E);
    }
    k_pool<<<dim3(B), dim3(64), 0, stream>>>(acc, b2, Bat, N,
                                             C1w, C1b, C2w, C2b, C3w, C3b,
                                             R1w, R1b, R2w, R2b, R3w, R3b,
                                             outp);
}

// Round 3
// 266.466 us; speedup vs baseline: 10.4829x; 1.4037x over previous
//
#include <hip/hip_runtime.h>
#include <hip/hip_bf16.h>
#include <float.h>

#define LRELU(x) ((x) > 0.0f ? (x) : 0.01f * (x))

typedef unsigned long long u64;

// ---------------------------------------------------------------------------
// K1: deg64 = (wsum=1.0 fixed Q8.32, cnt=0);  xw = X @ W1^T
// ---------------------------------------------------------------------------
__global__ __launch_bounds__(256) void k_init(const float* __restrict__ X,
                                              const float* __restrict__ W1,
                                              u64* __restrict__ deg64,
                                              float* __restrict__ xw, int N) {
    int i = blockIdx.x * blockDim.x + threadIdx.x;
    if (i >= N) return;
    deg64[i] = (u64)1 << 32;   // wsum = 1.0 (self loop), cnt = 0
    const float4 x = *reinterpret_cast<const float4*>(X + 4 * i);
    float o[16];
#pragma unroll
    for (int g = 0; g < 16; ++g) {
        const float4 wr = *reinterpret_cast<const float4*>(W1 + 4 * g);
        o[g] = x.x * wr.x + x.y * wr.y + x.z * wr.z + x.w * wr.w;
    }
    float4* dst = reinterpret_cast<float4*>(xw + 16 * i);
#pragma unroll
    for (int k = 0; k < 4; ++k)
        dst[k] = make_float4(o[4 * k], o[4 * k + 1], o[4 * k + 2], o[4 * k + 3]);
}

// ---------------------------------------------------------------------------
// K2: ONE u64 atomic per active edge: deg64[c] += (1<<40) | fix32(w).
// Returned old value's high bits = this edge's rank within bucket c.
// ---------------------------------------------------------------------------
__global__ __launch_bounds__(256) void k_count(const int* __restrict__ row,
                                               const int* __restrict__ col,
                                               const float* __restrict__ w,
                                               u64* __restrict__ deg64,
                                               unsigned char* __restrict__ rank, int E) {
    int e = blockIdx.x * blockDim.x + threadIdx.x;
    if (e >= E) return;
    int r = row[e], c = col[e];
    if (c <= r) return;
    u64 add = ((u64)1 << 40) | (u64)(w[e] * 4294967296.0f);
    u64 old = atomicAdd(deg64 + c, add);
    rank[e] = (unsigned char)(old >> 40);
}

// ---------------------------------------------------------------------------
// Scan stage 1: per-block (1024 elems) exclusive scan of cnt(=deg64>>40)
// ---------------------------------------------------------------------------
__global__ __launch_bounds__(256) void k_scan1(const u64* __restrict__ deg64,
                                               int* __restrict__ offs,
                                               int* __restrict__ partials, int N) {
    __shared__ int sm[256];
    int tid = threadIdx.x;
    int base = blockIdx.x * 1024 + tid * 4;
    int v[4];
    int s = 0;
#pragma unroll
    for (int k = 0; k < 4; ++k) {
        int idx = base + k;
        v[k] = (idx < N) ? (int)(deg64[idx] >> 40) : 0;
        s += v[k];
    }
    sm[tid] = s;
    __syncthreads();
    for (int off = 1; off < 256; off <<= 1) {
        int t = (tid >= off) ? sm[tid - off] : 0;
        __syncthreads();
        sm[tid] += t;
        __syncthreads();
    }
    int run = sm[tid] - s;
#pragma unroll
    for (int k = 0; k < 4; ++k) {
        int idx = base + k;
        if (idx < N) offs[idx] = run;
        run += v[k];
    }
    if (tid == 255) partials[blockIdx.x] = sm[255];
}

// ---------------------------------------------------------------------------
// Scan stage 2: exclusive scan of <=256 block totals; offs[N] = total
// ---------------------------------------------------------------------------
__global__ __launch_bounds__(256) void k_scan2(int* __restrict__ partials,
                                               int* __restrict__ offs, int nb, int N) {
    __shared__ int sm[256];
    int tid = threadIdx.x;
    int v = (tid < nb) ? partials[tid] : 0;
    sm[tid] = v;
    __syncthreads();
    for (int off = 1; off < 256; off <<= 1) {
        int t = (tid >= off) ? sm[tid - off] : 0;
        __syncthreads();
        sm[tid] += t;
        __syncthreads();
    }
    if (tid < nb) partials[tid] = sm[tid] - v;
    if (tid == nb - 1) offs[N] = sm[tid];
}

// ---------------------------------------------------------------------------
// Scan stage 3 + self-loop: offs += partials[blk];
// dinv = rsqrt(wsum); acc = dinv^2 * xw
// ---------------------------------------------------------------------------
__global__ __launch_bounds__(256) void k_self3(int* __restrict__ offs,
                                               const int* __restrict__ partials,
                                               const u64* __restrict__ deg64,
                                               float* __restrict__ dinv,
                                               const float* __restrict__ xw,
                                               float* __restrict__ acc, int N) {
    int i = blockIdx.x * blockDim.x + threadIdx.x;
    if (i >= N) return;
    offs[i] += partials[i >> 10];
    float wsum = (float)((double)(deg64[i] & (((u64)1 << 40) - 1)) * (1.0 / 4294967296.0));
    float d = rsqrtf(wsum);
    dinv[i] = d;
    float s = d * d;
    const float4* xs = reinterpret_cast<const float4*>(xw + 16 * i);
    float4* as = reinterpret_cast<float4*>(acc + 16 * i);
#pragma unroll
    for (int k = 0; k < 4; ++k) {
        float4 v = xs[k];
        as[k] = make_float4(s * v.x, s * v.y, s * v.z, s * v.w);
    }
}

// ---------------------------------------------------------------------------
// Fill CSR (NO atomics): pack[offs[c] + rank[e]] = (row, nrm)
// ---------------------------------------------------------------------------
__global__ __launch_bounds__(256) void k_fill(const int* __restrict__ row,
                                              const int* __restrict__ col,
                                              const float* __restrict__ w,
                                              const float* __restrict__ dinv,
                                              const int* __restrict__ offs,
                                              const unsigned char* __restrict__ rank,
                                              int2* __restrict__ pack, int E) {
    int e = blockIdx.x * blockDim.x + threadIdx.x;
    if (e >= E) return;
    int r = row[e], c = col[e];
    if (c <= r) return;
    float nrm = dinv[r] * w[e] * dinv[c];
    int pos = offs[c] + (int)rank[e];
    pack[pos] = make_int2(r, __float_as_int(nrm));
}

// ---------------------------------------------------------------------------
// Gather: thread (c,g): acc[c][g] += sum_j nrm_j * xw[r_j][g]   (no atomics)
// ---------------------------------------------------------------------------
__global__ __launch_bounds__(256) void k_gather(const int* __restrict__ offs,
                                                const int2* __restrict__ pack,
                                                const float* __restrict__ xw,
                                                float* __restrict__ acc, int N) {
    int t = blockIdx.x * blockDim.x + threadIdx.x;
    if (t >= 16 * N) return;
    int c = t >> 4, g = t & 15;
    int beg = offs[c], end = offs[c + 1];
    float a = acc[t];
    for (int j = beg; j < end; ++j) {
        int2 p = pack[j];
        a += __int_as_float(p.y) * xw[((size_t)p.x << 4) + g];
    }
    acc[t] = a;
}

// ---------------------------------------------------------------------------
// K5: h1 = lrelu(acc + b1); xw = h1 @ W2^T; acc = dinv^2 * xw
// ---------------------------------------------------------------------------
__global__ __launch_bounds__(256) void k_mid(const float* __restrict__ b1,
                                             const float* __restrict__ W2,
                                             const float* __restrict__ dinv,
                                             float* __restrict__ xw,
                                             float* __restrict__ acc, int N) {
    int i = blockIdx.x * blockDim.x + threadIdx.x;
    if (i >= N) return;
    float h[16];
#pragma unroll
    for (int g = 0; g < 16; ++g) {
        float v = acc[16 * i + g] + b1[g];
        h[g] = LRELU(v);
    }
    float d = dinv[i];
    float s = d * d;
#pragma unroll
    for (int g = 0; g < 16; ++g) {
        float a = 0.0f;
#pragma unroll
        for (int k = 0; k < 16; ++k) a += h[k] * W2[16 * g + k];
        xw[16 * i + g] = a;
        acc[16 * i + g] = s * a;
    }
}

// ---------------------------------------------------------------------------
// Fallback kernels (atomic scatter path, used only if ws too small)
// ---------------------------------------------------------------------------
__global__ __launch_bounds__(256) void k_initf(const float* __restrict__ X,
                                               const float* __restrict__ W1,
                                               float* __restrict__ deg,
                                               float* __restrict__ xw, int N) {
    int i = blockIdx.x * blockDim.x + threadIdx.x;
    if (i >= N) return;
    deg[i] = 1.0f;
    const float4 x = *reinterpret_cast<const float4*>(X + 4 * i);
    float o[16];
#pragma unroll
    for (int g = 0; g < 16; ++g) {
        const float4 wr = *reinterpret_cast<const float4*>(W1 + 4 * g);
        o[g] = x.x * wr.x + x.y * wr.y + x.z * wr.z + x.w * wr.w;
    }
    float4* dst = reinterpret_cast<float4*>(xw + 16 * i);
#pragma unroll
    for (int k = 0; k < 4; ++k)
        dst[k] = make_float4(o[4 * k], o[4 * k + 1], o[4 * k + 2], o[4 * k + 3]);
}

__global__ __launch_bounds__(256) void k_degf(const int* __restrict__ row,
                                              const int* __restrict__ col,
                                              const float* __restrict__ w,
                                              float* __restrict__ deg, int E) {
    int e = blockIdx.x * blockDim.x + threadIdx.x;
    if (e >= E) return;
    int r = row[e], c = col[e];
    if (c > r) atomicAdd(deg + c, w[e]);
}

__global__ __launch_bounds__(256) void k_self(float* __restrict__ deg_dinv,
                                              const float* __restrict__ xw,
                                              float* __restrict__ acc, int N) {
    int i = blockIdx.x * blockDim.x + threadIdx.x;
    if (i >= N) return;
    float d = rsqrtf(deg_dinv[i]);
    deg_dinv[i] = d;
    float s = d * d;
    const float4* xs = reinterpret_cast<const float4*>(xw + 16 * i);
    float4* as = reinterpret_cast<float4*>(acc + 16 * i);
#pragma unroll
    for (int k = 0; k < 4; ++k) {
        float4 v = xs[k];
        as[k] = make_float4(s * v.x, s * v.y, s * v.z, s * v.w);
    }
}

__global__ __launch_bounds__(256) void k_scatter(const int* __restrict__ row,
                                                 const int* __restrict__ col,
                                                 const float* __restrict__ w,
                                                 const float* __restrict__ dinv,
                                                 const float* __restrict__ xw,
                                                 float* __restrict__ acc, int E) {
    int e = blockIdx.x * blockDim.x + threadIdx.x;
    if (e >= E) return;
    int r = row[e], c = col[e];
    if (c <= r) return;
    float nrm = dinv[r] * w[e] * dinv[c];
    const float4* xr = reinterpret_cast<const float4*>(xw + 16 * r);
    float* ac = acc + 16 * c;
#pragma unroll
    for (int k = 0; k < 4; ++k) {
        float4 v = xr[k];
        atomicAdd(ac + 4 * k + 0, nrm * v.x);
        atomicAdd(ac + 4 * k + 1, nrm * v.y);
        atomicAdd(ac + 4 * k + 2, nrm * v.z);
        atomicAdd(ac + 4 * k + 3, nrm * v.w);
    }
}

// ---------------------------------------------------------------------------
// K7: per-graph mean/max pool over lrelu(acc + b2), then both MLP heads.
// ---------------------------------------------------------------------------
__global__ __launch_bounds__(64) void k_pool(const float* __restrict__ acc,
                                             const float* __restrict__ b2,
                                             const int* __restrict__ batching,
                                             int N,
                                             const float* __restrict__ C1w, const float* __restrict__ C1b,
                                             const float* __restrict__ C2w, const float* __restrict__ C2b,
                                             const float* __restrict__ C3w, const float* __restrict__ C3b,
                                             const float* __restrict__ R1w, const float* __restrict__ R1b,
                                             const float* __restrict__ R2w, const float* __restrict__ R2b,
                                             const float* __restrict__ R3w, const float* __restrict__ R3b,
                                             float* __restrict__ out) {
    int b = blockIdx.x;
    int t = threadIdx.x;
    __shared__ int s_se[2];
    __shared__ float sp[32];
    __shared__ float h1s[64];
    __shared__ float h2s[64];
    if (t < 2) {
        int target = b + t;
        int lo = 0, hi = N;
        while (lo < hi) {
            int mid = (lo + hi) >> 1;
            if (batching[mid] < target) lo = mid + 1; else hi = mid;
        }
        s_se[t] = lo;
    }
    __syncthreads();
    int start = s_se[0], end = s_se[1];
    int g = t & 15, sub = t >> 4;
    float bg = b2[g];
    float sum = 0.0f, mx = -FLT_MAX;
    for (int n = start + sub; n < end; n += 4) {
        float v = acc[16 * n + g] + bg;
        v = LRELU(v);
        sum += v;
        mx = fmaxf(mx, v);
    }
    sum += __shfl_down(sum, 32);
    mx = fmaxf(mx, __shfl_down(mx, 32));
    sum += __shfl_down(sum, 16);
    mx = fmaxf(mx, __shfl_down(mx, 16));
    if (t < 16) {
        float cnt = (float)(end - start);
        sp[t] = sum / fmaxf(cnt, 1.0f);
        sp[16 + t] = mx;
    }
    __syncthreads();
    int d = t & 31;
    const float* W1h = (t < 32) ? C1w : R1w;
    const float* b1h = (t < 32) ? C1b : R1b;
    float a1 = b1h[d];
#pragma unroll 4
    for (int k = 0; k < 32; ++k) a1 += sp[k] * W1h[32 * d + k];
    h1s[t] = LRELU(a1);
    __syncthreads();
    const float* W2h = (t < 32) ? C2w : R2w;
    const float* b2h = (t < 32) ? C2b : R2b;
    const float* h1base = h1s + (t < 32 ? 0 : 32);
    float a2 = b2h[d];
#pragma unroll 4
    for (int k = 0; k < 32; ++k) a2 += h1base[k] * W2h[32 * d + k];
    h2s[t] = LRELU(a2);
    __syncthreads();
    if (t == 0 || t == 32) {
        const float* w3 = (t == 0) ? C3w : R3w;
        float a3 = (t == 0) ? C3b[0] : R3b[0];
        const float* hb = h2s + t;
#pragma unroll 4
        for (int k = 0; k < 32; ++k) a3 += hb[k] * w3[k];
        out[2 * b + (t >> 5)] = a3;
    }
}

// ---------------------------------------------------------------------------
extern "C" void kernel_launch(void* const* d_in, const int* in_sizes, int n_in,
                              void* d_out, int out_size, void* d_ws, size_t ws_size,
                              hipStream_t stream) {
    const float* X   = (const float*)d_in[0];
    const int*   EI  = (const int*)d_in[1];
    const float* EW  = (const float*)d_in[2];
    const int*   Bat = (const int*)d_in[3];
    const float* W1  = (const float*)d_in[5];
    const float* b1  = (const float*)d_in[6];
    const float* W2  = (const float*)d_in[7];
    const float* b2  = (const float*)d_in[8];
    const float* C1w = (const float*)d_in[9];
    const float* C1b = (const float*)d_in[10];
    const float* C2w = (const float*)d_in[11];
    const float* C2b = (const float*)d_in[12];
    const float* C3w = (const float*)d_in[13];
    const float* C3b = (const float*)d_in[14];
    const float* R1w = (const float*)d_in[15];
    const float* R1b = (const float*)d_in[16];
    const float* R2w = (const float*)d_in[17];
    const float* R2b = (const float*)d_in[18];
    const float* R3w = (const float*)d_in[19];
    const float* R3b = (const float*)d_in[20];

    const int N = in_sizes[0] / 4;
    const int E = in_sizes[1] / 2;
    const int B = out_size / 2;
    const int* row = EI;
    const int* col = EI + E;

    float* outp = (float*)d_out;

    // workspace layout (words of 4B; d_ws assumed 8B-aligned)
    size_t off = 0;
    u64*   deg64 = (u64*)d_ws;            off += 2 * (size_t)N;       // N u64
    float* xw    = (float*)d_ws + off;    off += 16 * (size_t)N;      // 16N f32
    float* acc   = (float*)d_ws + off;    off += 16 * (size_t)N;      // 16N f32
    float* dinv  = (float*)d_ws + off;    off += (size_t)N;           // N f32
    int*   offs  = (int*)d_ws + off;      off += (size_t)N + 1;       // N+1 int
    int*   part  = (int*)d_ws + off;      off += 256;                 // partials
    unsigned char* rank = (unsigned char*)((int*)d_ws + off);
    off += ((size_t)E + 3) / 4;                                        // E u8
    off = (off + 1) & ~(size_t)1;                                      // 8B align
    int2*  pack  = (int2*)((int*)d_ws + off);                          // E int2
    size_t needed = off * 4 + (size_t)E * 8;

    const int nb = (N + 1023) / 1024;

    dim3 blk(256);
    dim3 gN((N + 255) / 256);
    dim3 gE((E + 255) / 256);
    dim3 gNG((16 * N + 255) / 256);

    if (needed <= ws_size && nb <= 256) {
        k_init <<<gN, blk, 0, stream>>>(X, W1, deg64, xw, N);
        k_count<<<gE, blk, 0, stream>>>(row, col, EW, deg64, rank, E);
        k_scan1<<<dim3(nb), blk, 0, stream>>>(deg64, offs, part, N);
        k_scan2<<<dim3(1), blk, 0, stream>>>(part, offs, nb, N);
        k_self3<<<gN, blk, 0, stream>>>(offs, part, deg64, dinv, xw, acc, N);
        k_fill <<<gE, blk, 0, stream>>>(row, col, EW, dinv, offs, rank, pack, E);
        k_gather<<<gNG, blk, 0, stream>>>(offs, pack, xw, acc, N);
        k_mid  <<<gN, blk, 0, stream>>>(b1, W2, dinv, xw, acc, N);
        k_gather<<<gNG, blk, 0, stream>>>(offs, pack, xw, acc, N);
        k_pool<<<dim3(B), dim3(64), 0, stream>>>(acc, b2, Bat, N,
                                                 C1w, C1b, C2w, C2b, C3w, C3b,
                                                 R1w, R1b, R2w, R2b, R3w, R3b,
                                                 outp);
    } else {
        // fallback: atomic scatter path (needs only deg/xw/acc)
        float* deg = (float*)d_ws;
        k_initf<<<gN, blk, 0, stream>>>(X, W1, deg, xw, N);
        k_degf <<<gE, blk, 0, stream>>>(row, col, EW, deg, E);
        k_self <<<gN, blk, 0, stream>>>(deg, xw, acc, N);
        k_scatter<<<gE, blk, 0, stream>>>(row, col, EW, deg, xw, acc, E);
        k_mid  <<<gN, blk, 0, stream>>>(b1, W2, deg, xw, acc, N);
        k_scatter<<<gE, blk, 0, stream>>>(row, col, EW, deg, xw, acc, E);
        k_pool<<<dim3(B), dim3(64), 0, stream>>>(acc, b2, Bat, N,
                                                 C1w, C1b, C2w, C2b, C3w, C3b,
                                                 R1w, R1b, R2w, R2b, R3w, R3b,
                                                 outp);
    }
}

// Round 4
// 252.466 us; speedup vs baseline: 11.0642x; 1.0555x over previous
//
#include <hip/hip_runtime.h>
#include <hip/hip_bf16.h>
#include <float.h>

#define LRELU(x) ((x) > 0.0f ? (x) : 0.01f * (x))

typedef unsigned long long u64;
#define MASK40 (((u64)1 << 40) - 1)

// ---------------------------------------------------------------------------
// K0: deg64 = (wsum = 1.0 in Q8.32, cnt = 0)  -- self loop
// ---------------------------------------------------------------------------
__global__ __launch_bounds__(256) void k_zero(u64* __restrict__ deg64, int N) {
    int i = blockIdx.x * blockDim.x + threadIdx.x;
    if (i < N) deg64[i] = (u64)1 << 32;
}

// ---------------------------------------------------------------------------
// K1 (fused): blocks < gE: one u64 atomic per active edge
//             deg64[c] += (1<<40)|fix32(w); rank[e] = old>>40
//             blocks >= gE: xw1 = X @ W1^T  (independent work, fills idle VALU)
// ---------------------------------------------------------------------------
__global__ __launch_bounds__(256) void k_countx(const int* __restrict__ row,
                                                const int* __restrict__ col,
                                                const float* __restrict__ w,
                                                const float* __restrict__ X,
                                                const float* __restrict__ W1,
                                                u64* __restrict__ deg64,
                                                unsigned char* __restrict__ rank,
                                                float* __restrict__ xw1,
                                                int E, int N, int gE) {
    int tid = threadIdx.x;
    if ((int)blockIdx.x < gE) {
        int e = blockIdx.x * 256 + tid;
        if (e >= E) return;
        int r = row[e], c = col[e];
        if (c <= r) return;
        u64 add = ((u64)1 << 40) | (u64)(w[e] * 4294967296.0f);
        u64 old = atomicAdd(deg64 + c, add);
        rank[e] = (unsigned char)(old >> 40);
    } else {
        int i = (blockIdx.x - gE) * 256 + tid;
        if (i >= N) return;
        const float4 x = *reinterpret_cast<const float4*>(X + 4 * i);
        float o[16];
#pragma unroll
        for (int g = 0; g < 16; ++g) {
            const float4 wr = *reinterpret_cast<const float4*>(W1 + 4 * g);
            o[g] = x.x * wr.x + x.y * wr.y + x.z * wr.z + x.w * wr.w;
        }
        float4* dst = reinterpret_cast<float4*>(xw1 + 16 * i);
#pragma unroll
        for (int k = 0; k < 4; ++k)
            dst[k] = make_float4(o[4 * k], o[4 * k + 1], o[4 * k + 2], o[4 * k + 3]);
    }
}

// ---------------------------------------------------------------------------
// K2: per-block (1024 elems) exclusive scan of cnt(=deg64>>40); also
//     dinv[i] = rsqrt(wsum)
// ---------------------------------------------------------------------------
__global__ __launch_bounds__(256) void k_scan1(const u64* __restrict__ deg64,
                                               int* __restrict__ offs,
                                               int* __restrict__ partials,
                                               float* __restrict__ dinv, int N) {
    __shared__ int sm[256];
    int tid = threadIdx.x;
    int base = blockIdx.x * 1024 + tid * 4;
    int v[4];
    float dv[4];
    int s = 0;
#pragma unroll
    for (int k = 0; k < 4; ++k) {
        int idx = base + k;
        u64 d = (idx < N) ? deg64[idx] : ((u64)1 << 32);
        v[k] = (int)(d >> 40);
        float wsum = (float)((double)(d & MASK40) * (1.0 / 4294967296.0));
        dv[k] = rsqrtf(wsum);
        s += v[k];
    }
    if (base + 3 < N) {
        *reinterpret_cast<float4*>(dinv + base) = make_float4(dv[0], dv[1], dv[2], dv[3]);
    } else {
#pragma unroll
        for (int k = 0; k < 4; ++k) if (base + k < N) dinv[base + k] = dv[k];
    }
    sm[tid] = s;
    __syncthreads();
    for (int off = 1; off < 256; off <<= 1) {
        int t = (tid >= off) ? sm[tid - off] : 0;
        __syncthreads();
        sm[tid] += t;
        __syncthreads();
    }
    int run = sm[tid] - s;
#pragma unroll
    for (int k = 0; k < 4; ++k) {
        int idx = base + k;
        if (idx < N) offs[idx] = run;
        run += v[k];
    }
    if (tid == 255) partials[blockIdx.x] = sm[255];
}

// ---------------------------------------------------------------------------
// K3: exclusive scan of <=256 block totals; offs[N] = grand total
// ---------------------------------------------------------------------------
__global__ __launch_bounds__(256) void k_scan2(int* __restrict__ partials,
                                               int* __restrict__ offs, int nb, int N) {
    __shared__ int sm[256];
    int tid = threadIdx.x;
    int v = (tid < nb) ? partials[tid] : 0;
    sm[tid] = v;
    __syncthreads();
    for (int off = 1; off < 256; off <<= 1) {
        int t = (tid >= off) ? sm[tid - off] : 0;
        __syncthreads();
        sm[tid] += t;
        __syncthreads();
    }
    if (tid < nb) partials[tid] = sm[tid] - v;
    if (tid == nb - 1) offs[N] = sm[tid];
}

// ---------------------------------------------------------------------------
// K4 (fused): blocks < gE: pack[offs[c]+part[c>>10]+rank[e]] = (row, nrm)
//             blocks >= gE: offsF[i] = offs[i] + part[i>>10]; offsF[N]=offs[N]
// ---------------------------------------------------------------------------
__global__ __launch_bounds__(256) void k_fillx(const int* __restrict__ row,
                                               const int* __restrict__ col,
                                               const float* __restrict__ w,
                                               const float* __restrict__ dinv,
                                               const int* __restrict__ offs,
                                               const int* __restrict__ part,
                                               const unsigned char* __restrict__ rank,
                                               int2* __restrict__ pack,
                                               int* __restrict__ offsF,
                                               int E, int N, int gE) {
    int tid = threadIdx.x;
    if ((int)blockIdx.x < gE) {
        int e = blockIdx.x * 256 + tid;
        if (e >= E) return;
        int r = row[e], c = col[e];
        if (c <= r) return;
        float nrm = dinv[r] * w[e] * dinv[c];
        int pos = offs[c] + part[c >> 10] + (int)rank[e];
        pack[pos] = make_int2(r, __float_as_int(nrm));
    } else {
        int i = (blockIdx.x - gE) * 256 + tid;
        if (i == 0) offsF[N] = offs[N];
        if (i >= N) return;
        offsF[i] = offs[i] + part[i >> 10];
    }
}

// ---------------------------------------------------------------------------
// K5: gather layer1 + fused mid-transform:
//   a = dinv[c]^2 * xw1[c,g] + sum_j nrm_j * xw1[r_j,g]
//   h = lrelu(a + b1[g]);  xw2[c,g'] = sum_k h[k] * W2[g',k]  (in-wave shfl)
// ---------------------------------------------------------------------------
__global__ __launch_bounds__(256) void k_gather1m(const int* __restrict__ offsF,
                                                  const int2* __restrict__ pack,
                                                  const float* __restrict__ xw1,
                                                  const float* __restrict__ dinv,
                                                  const float* __restrict__ b1,
                                                  const float* __restrict__ W2,
                                                  float* __restrict__ xw2, int N) {
    int t = blockIdx.x * blockDim.x + threadIdx.x;
    int NT = 16 * N;
    bool valid = t < NT;
    int tc = valid ? t : NT - 1;
    int c = tc >> 4, g = tc & 15;
    int beg = offsF[c], end = offsF[c + 1];
    float d = dinv[c];
    float a = d * d * xw1[tc];
    for (int j = beg; j < end; ++j) {
        int2 p = pack[j];
        a += __int_as_float(p.y) * xw1[((size_t)p.x << 4) + g];
    }
    float h = a + b1[g];
    h = LRELU(h);
    // in-wave 16x16 transform: lanes [base, base+16) hold node's 16 dims
    int lane = threadIdx.x & 63;
    int base = lane & 48;
    const float4* W2r = reinterpret_cast<const float4*>(W2 + 16 * g);
    float4 w0 = W2r[0], w1 = W2r[1], w2 = W2r[2], w3 = W2r[3];
    float o = 0.0f;
    o += __shfl(h, base + 0) * w0.x;
    o += __shfl(h, base + 1) * w0.y;
    o += __shfl(h, base + 2) * w0.z;
    o += __shfl(h, base + 3) * w0.w;
    o += __shfl(h, base + 4) * w1.x;
    o += __shfl(h, base + 5) * w1.y;
    o += __shfl(h, base + 6) * w1.z;
    o += __shfl(h, base + 7) * w1.w;
    o += __shfl(h, base + 8) * w2.x;
    o += __shfl(h, base + 9) * w2.y;
    o += __shfl(h, base + 10) * w2.z;
    o += __shfl(h, base + 11) * w2.w;
    o += __shfl(h, base + 12) * w3.x;
    o += __shfl(h, base + 13) * w3.y;
    o += __shfl(h, base + 14) * w3.z;
    o += __shfl(h, base + 15) * w3.w;
    if (valid) xw2[t] = o;
}

// ---------------------------------------------------------------------------
// K6: gather layer2 + fused b2 + lrelu:  acc = lrelu(dinv^2*xw2[c]+sum + b2)
// ---------------------------------------------------------------------------
__global__ __launch_bounds__(256) void k_gather2(const int* __restrict__ offsF,
                                                 const int2* __restrict__ pack,
                                                 const float* __restrict__ xw2,
                                                 const float* __restrict__ dinv,
                                                 const float* __restrict__ b2,
                                                 float* __restrict__ acc, int N) {
    int t = blockIdx.x * blockDim.x + threadIdx.x;
    if (t >= 16 * N) return;
    int c = t >> 4, g = t & 15;
    int beg = offsF[c], end = offsF[c + 1];
    float d = dinv[c];
    float a = d * d * xw2[t];
    for (int j = beg; j < end; ++j) {
        int2 p = pack[j];
        a += __int_as_float(p.y) * xw2[((size_t)p.x << 4) + g];
    }
    a += b2[g];
    acc[t] = LRELU(a);
}

// ---------------------------------------------------------------------------
// K7: per-graph mean/max pool over acc (already activated), then MLP heads.
// ---------------------------------------------------------------------------
__global__ __launch_bounds__(64) void k_poolA(const float* __restrict__ acc,
                                              const int* __restrict__ batching,
                                              int N,
                                              const float* __restrict__ C1w, const float* __restrict__ C1b,
                                              const float* __restrict__ C2w, const float* __restrict__ C2b,
                                              const float* __restrict__ C3w, const float* __restrict__ C3b,
                                              const float* __restrict__ R1w, const float* __restrict__ R1b,
                                              const float* __restrict__ R2w, const float* __restrict__ R2b,
                                              const float* __restrict__ R3w, const float* __restrict__ R3b,
                                              float* __restrict__ out) {
    int b = blockIdx.x;
    int t = threadIdx.x;
    __shared__ int s_se[2];
    __shared__ float sp[32];
    __shared__ float h1s[64];
    __shared__ float h2s[64];
    if (t < 2) {
        int target = b + t;
        int lo = 0, hi = N;
        while (lo < hi) {
            int mid = (lo + hi) >> 1;
            if (batching[mid] < target) lo = mid + 1; else hi = mid;
        }
        s_se[t] = lo;
    }
    __syncthreads();
    int start = s_se[0], end = s_se[1];
    int g = t & 15, sub = t >> 4;
    float sum = 0.0f, mx = -FLT_MAX;
    for (int n = start + sub; n < end; n += 4) {
        float v = acc[16 * n + g];
        sum += v;
        mx = fmaxf(mx, v);
    }
    sum += __shfl_down(sum, 32);
    mx = fmaxf(mx, __shfl_down(mx, 32));
    sum += __shfl_down(sum, 16);
    mx = fmaxf(mx, __shfl_down(mx, 16));
    if (t < 16) {
        float cnt = (float)(end - start);
        sp[t] = sum / fmaxf(cnt, 1.0f);
        sp[16 + t] = mx;
    }
    __syncthreads();
    int d = t & 31;
    const float* W1h = (t < 32) ? C1w : R1w;
    const float* b1h = (t < 32) ? C1b : R1b;
    float a1 = b1h[d];
#pragma unroll 4
    for (int k = 0; k < 32; ++k) a1 += sp[k] * W1h[32 * d + k];
    h1s[t] = LRELU(a1);
    __syncthreads();
    const float* W2h = (t < 32) ? C2w : R2w;
    const float* b2h = (t < 32) ? C2b : R2b;
    const float* h1base = h1s + (t < 32 ? 0 : 32);
    float a2 = b2h[d];
#pragma unroll 4
    for (int k = 0; k < 32; ++k) a2 += h1base[k] * W2h[32 * d + k];
    h2s[t] = LRELU(a2);
    __syncthreads();
    if (t == 0 || t == 32) {
        const float* w3 = (t == 0) ? C3w : R3w;
        float a3 = (t == 0) ? C3b[0] : R3b[0];
        const float* hb = h2s + t;
#pragma unroll 4
        for (int k = 0; k < 32; ++k) a3 += hb[k] * w3[k];
        out[2 * b + (t >> 5)] = a3;
    }
}

// ---------------------------------------------------------------------------
// Fallback kernels (atomic scatter path, used only if ws too small)
// ---------------------------------------------------------------------------
__global__ __launch_bounds__(256) void k_initf(const float* __restrict__ X,
                                               const float* __restrict__ W1,
                                               float* __restrict__ deg,
                                               float* __restrict__ xw, int N) {
    int i = blockIdx.x * blockDim.x + threadIdx.x;
    if (i >= N) return;
    deg[i] = 1.0f;
    const float4 x = *reinterpret_cast<const float4*>(X + 4 * i);
    float o[16];
#pragma unroll
    for (int g = 0; g < 16; ++g) {
        const float4 wr = *reinterpret_cast<const float4*>(W1 + 4 * g);
        o[g] = x.x * wr.x + x.y * wr.y + x.z * wr.z + x.w * wr.w;
    }
    float4* dst = reinterpret_cast<float4*>(xw + 16 * i);
#pragma unroll
    for (int k = 0; k < 4; ++k)
        dst[k] = make_float4(o[4 * k], o[4 * k + 1], o[4 * k + 2], o[4 * k + 3]);
}

__global__ __launch_bounds__(256) void k_degf(const int* __restrict__ row,
                                              const int* __restrict__ col,
                                              const float* __restrict__ w,
                                              float* __restrict__ deg, int E) {
    int e = blockIdx.x * blockDim.x + threadIdx.x;
    if (e >= E) return;
    int r = row[e], c = col[e];
    if (c > r) atomicAdd(deg + c, w[e]);
}

__global__ __launch_bounds__(256) void k_self(float* __restrict__ deg_dinv,
                                              const float* __restrict__ xw,
                                              float* __restrict__ acc, int N) {
    int i = blockIdx.x * blockDim.x + threadIdx.x;
    if (i >= N) return;
    float d = rsqrtf(deg_dinv[i]);
    deg_dinv[i] = d;
    float s = d * d;
    const float4* xs = reinterpret_cast<const float4*>(xw + 16 * i);
    float4* as = reinterpret_cast<float4*>(acc + 16 * i);
#pragma unroll
    for (int k = 0; k < 4; ++k) {
        float4 v = xs[k];
        as[k] = make_float4(s * v.x, s * v.y, s * v.z, s * v.w);
    }
}

__global__ __launch_bounds__(256) void k_scatter(const int* __restrict__ row,
                                                 const int* __restrict__ col,
                                                 const float* __restrict__ w,
                                                 const float* __restrict__ dinv,
                                                 const float* __restrict__ xw,
                                                 float* __restrict__ acc, int E) {
    int e = blockIdx.x * blockDim.x + threadIdx.x;
    if (e >= E) return;
    int r = row[e], c = col[e];
    if (c <= r) return;
    float nrm = dinv[r] * w[e] * dinv[c];
    const float4* xr = reinterpret_cast<const float4*>(xw + 16 * r);
    float* ac = acc + 16 * c;
#pragma unroll
    for (int k = 0; k < 4; ++k) {
        float4 v = xr[k];
        atomicAdd(ac + 4 * k + 0, nrm * v.x);
        atomicAdd(ac + 4 * k + 1, nrm * v.y);
        atomicAdd(ac + 4 * k + 2, nrm * v.z);
        atomicAdd(ac + 4 * k + 3, nrm * v.w);
    }
}

__global__ __launch_bounds__(256) void k_mid(const float* __restrict__ b1,
                                             const float* __restrict__ W2,
                                             const float* __restrict__ dinv,
                                             float* __restrict__ xw,
                                             float* __restrict__ acc, int N) {
    int i = blockIdx.x * blockDim.x + threadIdx.x;
    if (i >= N) return;
    float h[16];
#pragma unroll
    for (int g = 0; g < 16; ++g) {
        float v = acc[16 * i + g] + b1[g];
        h[g] = LRELU(v);
    }
    float d = dinv[i];
    float s = d * d;
#pragma unroll
    for (int g = 0; g < 16; ++g) {
        float a = 0.0f;
#pragma unroll
        for (int k = 0; k < 16; ++k) a += h[k] * W2[16 * g + k];
        xw[16 * i + g] = a;
        acc[16 * i + g] = s * a;
    }
}

__global__ __launch_bounds__(256) void k_act(const float* __restrict__ b2,
                                             float* __restrict__ acc, int NT) {
    int t = blockIdx.x * blockDim.x + threadIdx.x;
    if (t >= NT) return;
    float v = acc[t] + b2[t & 15];
    acc[t] = LRELU(v);
}

// ---------------------------------------------------------------------------
extern "C" void kernel_launch(void* const* d_in, const int* in_sizes, int n_in,
                              void* d_out, int out_size, void* d_ws, size_t ws_size,
                              hipStream_t stream) {
    const float* X   = (const float*)d_in[0];
    const int*   EI  = (const int*)d_in[1];
    const float* EW  = (const float*)d_in[2];
    const int*   Bat = (const int*)d_in[3];
    const float* W1  = (const float*)d_in[5];
    const float* b1  = (const float*)d_in[6];
    const float* W2  = (const float*)d_in[7];
    const float* b2  = (const float*)d_in[8];
    const float* C1w = (const float*)d_in[9];
    const float* C1b = (const float*)d_in[10];
    const float* C2w = (const float*)d_in[11];
    const float* C2b = (const float*)d_in[12];
    const float* C3w = (const float*)d_in[13];
    const float* C3b = (const float*)d_in[14];
    const float* R1w = (const float*)d_in[15];
    const float* R1b = (const float*)d_in[16];
    const float* R2w = (const float*)d_in[17];
    const float* R2b = (const float*)d_in[18];
    const float* R3w = (const float*)d_in[19];
    const float* R3b = (const float*)d_in[20];

    const int N = in_sizes[0] / 4;
    const int E = in_sizes[1] / 2;
    const int B = out_size / 2;
    const int* row = EI;
    const int* col = EI + E;

    float* outp = (float*)d_out;

    // workspace layout (4B words; d_ws 8B-aligned)
    size_t off = 0;
    u64*   deg64 = (u64*)d_ws;            off += 2 * (size_t)N;       // N u64
    float* xw1   = (float*)d_ws + off;    off += 16 * (size_t)N;      // 16N (reused as acc)
    float* xw2   = (float*)d_ws + off;    off += 16 * (size_t)N;      // 16N
    float* dinv  = (float*)d_ws + off;    off += (size_t)N;           // N
    int*   offs  = (int*)d_ws + off;      off += (size_t)N + 1;       // N+1
    int*   offsF = (int*)d_ws + off;      off += (size_t)N + 1;       // N+1
    int*   part  = (int*)d_ws + off;      off += 256;                 // partials
    unsigned char* rank = (unsigned char*)((int*)d_ws + off);
    off += ((size_t)E + 3) / 4;                                        // E u8
    off = (off + 1) & ~(size_t)1;                                      // 8B align
    int2*  pack  = (int2*)((int*)d_ws + off);                          // <=E int2
    size_t needed = off * 4 + (size_t)E * 8;

    const int nb = (N + 1023) / 1024;

    dim3 blk(256);
    const int gN  = (N + 255) / 256;
    const int gE  = (E + 255) / 256;
    const int gNG = (16 * N + 255) / 256;

    if (needed <= ws_size && nb <= 256) {
        float* acc = xw1;  // xw1 dead after gather1m
        k_zero  <<<dim3(gN), blk, 0, stream>>>(deg64, N);
        k_countx<<<dim3(gE + gN), blk, 0, stream>>>(row, col, EW, X, W1,
                                                    deg64, rank, xw1, E, N, gE);
        k_scan1 <<<dim3(nb), blk, 0, stream>>>(deg64, offs, part, dinv, N);
        k_scan2 <<<dim3(1), blk, 0, stream>>>(part, offs, nb, N);
        k_fillx <<<dim3(gE + gN), blk, 0, stream>>>(row, col, EW, dinv, offs, part,
                                                    rank, pack, offsF, E, N, gE);
        k_gather1m<<<dim3(gNG), blk, 0, stream>>>(offsF, pack, xw1, dinv, b1, W2, xw2, N);
        k_gather2 <<<dim3(gNG), blk, 0, stream>>>(offsF, pack, xw2, dinv, b2, acc, N);
        k_poolA <<<dim3(B), dim3(64), 0, stream>>>(acc, Bat, N,
                                                   C1w, C1b, C2w, C2b, C3w, C3b,
                                                   R1w, R1b, R2w, R2b, R3w, R3b,
                                                   outp);
    } else {
        // fallback: atomic scatter path
        float* deg = (float*)d_ws;
        float* xw  = (float*)d_ws + N;
        float* acc = xw + 16 * (size_t)N;
        k_initf<<<dim3(gN), blk, 0, stream>>>(X, W1, deg, xw, N);
        k_degf <<<dim3(gE), blk, 0, stream>>>(row, col, EW, deg, E);
        k_self <<<dim3(gN), blk, 0, stream>>>(deg, xw, acc, N);
        k_scatter<<<dim3(gE), blk, 0, stream>>>(row, col, EW, deg, xw, acc, E);
        k_mid  <<<dim3(gN), blk, 0, stream>>>(b1, W2, deg, xw, acc, N);
        k_scatter<<<dim3(gE), blk, 0, stream>>>(row, col, EW, deg, xw, acc, E);
        k_act  <<<dim3(gNG), blk, 0, stream>>>(b2, acc, 16 * N);
        k_poolA<<<dim3(B), dim3(64), 0, stream>>>(acc, Bat, N,
                                                  C1w, C1b, C2w, C2b, C3w, C3b,
                                                  R1w, R1b, R2w, R2b, R3w, R3b,
                                                  outp);
    }
}